// Round 3
// baseline (602.816 us; speedup 1.0000x reference)
//
#include <hip/hip_runtime.h>
#include <hip/hip_bf16.h>
#include <stdint.h>

// B=8, N=2048, E=1024, H=16, D=64 -> M = B*N = 16384.
// qkv row layout per token: [3][H=16][D=64] = 3072 elems

typedef __attribute__((ext_vector_type(8))) short short8;
typedef __attribute__((ext_vector_type(8))) unsigned short ushort8;
typedef __attribute__((ext_vector_type(16))) float floatx16;

__device__ __forceinline__ unsigned short f2bf(float f) {
  union { float f; uint32_t u; } x; x.f = f;
  uint32_t u = x.u;
  return (unsigned short)((u + 0x7fffu + ((u >> 16) & 1u)) >> 16);  // RNE
}
__device__ __forceinline__ float bf2f(unsigned short s) {
  union { uint32_t u; float f; } x; x.u = ((uint32_t)s) << 16; return x.f;
}

// ---------------- fused fp32 -> bf16 cast for all three tensors ----------------
// region sizes in 8-elem groups: x 2,097,152 | Wqkv 393,216 | Wo 131,072 -> 2,621,440 total
__global__ __launch_bounds__(256) void cvt_all(const float* __restrict__ x,
                                               const float* __restrict__ w1,
                                               const float* __restrict__ w2,
                                               unsigned short* __restrict__ xb,
                                               unsigned short* __restrict__ w1b,
                                               unsigned short* __restrict__ w2b) {
  int i = blockIdx.x * 256 + threadIdx.x;
  const float* src;
  unsigned short* dst;
  if (i < 2097152) {
    src = x; dst = xb;
  } else if (i < 2097152 + 393216) {
    i -= 2097152; src = w1; dst = w1b;
  } else {
    i -= 2490368; src = w2; dst = w2b;
  }
  long base = (long)i * 8;
  const float4* p = (const float4*)(src + base);
  float4 a = p[0], b = p[1];
  ushort8 r;
  r[0] = f2bf(a.x); r[1] = f2bf(a.y); r[2] = f2bf(a.z); r[3] = f2bf(a.w);
  r[4] = f2bf(b.x); r[5] = f2bf(b.y); r[6] = f2bf(b.z); r[7] = f2bf(b.w);
  *(ushort8*)(dst + base) = r;
}

// ---------------- async global->LDS, 16B per lane ----------------
__device__ __forceinline__ void gl2lds16(const void* g, void* l) {
  __builtin_amdgcn_global_load_lds(
      (const uint32_t __attribute__((address_space(1)))*)g,
      (uint32_t __attribute__((address_space(3)))*)(uint32_t)(uintptr_t)l,
      16, 0, 0);
}

// ---------------- bf16 GEMM v3: C[M,N] = A[M,K]*B[N,K]^T + bias[N] ----------------
// Block tile 128(M)x256(N), BK=64, 4 waves in 2x2; wave tile 64x128 = 2x4 of
// mfma_f32_32x32x16_bf16. LDS: 16B chunks at L = r*8 + (c ^ (r&7)) (XOR swizzle:
// staging stays lane-contiguous for global_load_lds, fragment ds_read_b128 is
// bank-uniform). 48 KB LDS, ~190 VGPR -> 2 blocks/CU.
template <bool OUT_BF16>
__device__ __forceinline__ void gemm_core(const unsigned short* __restrict__ A,
                                          const unsigned short* __restrict__ Bm,
                                          const float* __restrict__ bias,
                                          void* __restrict__ Cout, int N, int K) {
  __shared__ __align__(16) unsigned short lA[128 * 64];  // 16 KB
  __shared__ __align__(16) unsigned short lB[256 * 64];  // 32 KB
  const int tid = threadIdx.x;
  const int lane = tid & 63;
  const int wave = tid >> 6;
  const long row0 = (long)blockIdx.y * 128;
  const long col0 = (long)blockIdx.x * 256;
  const int wr = (wave >> 1) * 64;    // wave row offset
  const int wc = (wave & 1) * 128;    // wave col offset
  const int l32 = lane & 31;
  const int lhi = lane >> 5;
  const int l7 = lane & 7;

  floatx16 acc[2][4] = {};

  // staging: chunk L = p*256 + tid; r = p*32 + (tid>>3); global c = (tid&7)^(r&7)
  const int rstage = tid >> 3;
  const int cstage = (tid & 7) ^ (rstage & 7);
  const unsigned short* gA0 = A + (row0 + rstage) * (long)K + cstage * 8;
  const unsigned short* gB0 = Bm + (col0 + rstage) * (long)K + cstage * 8;
  char* ldsA0 = (char*)lA + tid * 16;
  char* ldsB0 = (char*)lB + tid * 16;
  const long rowstep = (long)32 * K;

  // fragment offsets: row r stored at byte r*128 + ((chunk)^l7)*16, chunk = 2s+lhi
  int aRow[2], bRow[4], sOff[4];
#pragma unroll
  for (int i = 0; i < 2; i++) aRow[i] = (wr + i * 32 + l32) * 128;
#pragma unroll
  for (int j = 0; j < 4; j++) bRow[j] = (wc + j * 32 + l32) * 128;
#pragma unroll
  for (int s = 0; s < 4; s++) sOff[s] = ((2 * s + lhi) ^ l7) * 16;

  for (int k0 = 0; k0 < K; k0 += 64) {
    __syncthreads();
#pragma unroll
    for (int p = 0; p < 4; p++)
      gl2lds16(gA0 + p * rowstep + k0, ldsA0 + p * 4096);
#pragma unroll
    for (int p = 0; p < 8; p++)
      gl2lds16(gB0 + p * rowstep + k0, ldsB0 + p * 4096);
    __syncthreads();

#pragma unroll
    for (int s = 0; s < 4; s++) {
      short8 a0 = *(const short8*)((char*)lA + aRow[0] + sOff[s]);
      short8 a1 = *(const short8*)((char*)lA + aRow[1] + sOff[s]);
      short8 b0 = *(const short8*)((char*)lB + bRow[0] + sOff[s]);
      short8 b1 = *(const short8*)((char*)lB + bRow[1] + sOff[s]);
      short8 b2 = *(const short8*)((char*)lB + bRow[2] + sOff[s]);
      short8 b3 = *(const short8*)((char*)lB + bRow[3] + sOff[s]);
      acc[0][0] = __builtin_amdgcn_mfma_f32_32x32x16_bf16(a0, b0, acc[0][0], 0, 0, 0);
      acc[0][1] = __builtin_amdgcn_mfma_f32_32x32x16_bf16(a0, b1, acc[0][1], 0, 0, 0);
      acc[0][2] = __builtin_amdgcn_mfma_f32_32x32x16_bf16(a0, b2, acc[0][2], 0, 0, 0);
      acc[0][3] = __builtin_amdgcn_mfma_f32_32x32x16_bf16(a0, b3, acc[0][3], 0, 0, 0);
      acc[1][0] = __builtin_amdgcn_mfma_f32_32x32x16_bf16(a1, b0, acc[1][0], 0, 0, 0);
      acc[1][1] = __builtin_amdgcn_mfma_f32_32x32x16_bf16(a1, b1, acc[1][1], 0, 0, 0);
      acc[1][2] = __builtin_amdgcn_mfma_f32_32x32x16_bf16(a1, b2, acc[1][2], 0, 0, 0);
      acc[1][3] = __builtin_amdgcn_mfma_f32_32x32x16_bf16(a1, b3, acc[1][3], 0, 0, 0);
    }
  }

  // epilogue: C/D layout col = lane&31, row = (reg&3) + 8*(reg>>2) + 4*(lane>>5)
  float bv[4];
#pragma unroll
  for (int j = 0; j < 4; j++) bv[j] = bias[col0 + wc + j * 32 + l32];

#pragma unroll
  for (int i = 0; i < 2; i++) {
#pragma unroll
    for (int j = 0; j < 4; j++) {
      const long col = col0 + wc + j * 32 + l32;
      const long rbase = row0 + wr + i * 32 + 4 * lhi;
#pragma unroll
      for (int reg = 0; reg < 16; reg++) {
        const long row = rbase + (reg & 3) + 8 * (reg >> 2);
        float v = acc[i][j][reg] + bv[j];
        if (OUT_BF16)
          ((unsigned short*)Cout)[row * N + col] = f2bf(v);
        else
          ((float*)Cout)[row * N + col] = v;
      }
    }
  }
}

__global__ __launch_bounds__(256, 2) void gemm_qkv(const unsigned short* __restrict__ A,
                                                   const unsigned short* __restrict__ Bm,
                                                   const float* __restrict__ bias,
                                                   unsigned short* __restrict__ Cout,
                                                   int N, int K) {
  gemm_core<true>(A, Bm, bias, Cout, N, K);
}

__global__ __launch_bounds__(256, 2) void gemm_out(const unsigned short* __restrict__ A,
                                                   const unsigned short* __restrict__ Bm,
                                                   const float* __restrict__ bias,
                                                   float* __restrict__ Cout,
                                                   int N, int K) {
  gemm_core<false>(A, Bm, bias, Cout, N, K);
}

// ---------------- per-token cross-head attention ----------------
// energy[b,s,i,j] = sum_d Q[b,s,i,d]*K[b,s,j,d] / 32; softmax over j; out = A*V,
// raw-reshape scramble: row = b*2048 + i*128 + s/16, col = (s%16)*64 + d.
__global__ __launch_bounds__(256) void attn_kernel(const unsigned short* __restrict__ qkv,
                                                   unsigned short* __restrict__ out2) {
  const int t = blockIdx.x * 256 + threadIdx.x;  // (token, head)
  const int head = t & 15;
  const int token = t >> 4;
  const int b = token >> 11;
  const int s = token & 2047;
  const unsigned short* base = qkv + (long)token * 3072;

  float qf[64];
  {
    const uint4* qp = (const uint4*)(base + head * 64);
#pragma unroll
    for (int w = 0; w < 8; w++) {
      uint4 u = qp[w];
      uint32_t arr[4] = {u.x, u.y, u.z, u.w};
#pragma unroll
      for (int c = 0; c < 4; c++) {
        qf[w * 8 + c * 2 + 0] = bf2f((unsigned short)(arr[c] & 0xffffu));
        qf[w * 8 + c * 2 + 1] = bf2f((unsigned short)(arr[c] >> 16));
      }
    }
  }

  float e[16];
  const unsigned short* kbase = base + 1024;
#pragma unroll
  for (int j = 0; j < 16; j++) {
    const uint4* kp = (const uint4*)(kbase + j * 64);
    // 4 partial accumulators to break the serial FMA chain (no fast-math reassoc)
    float a0 = 0.f, a1 = 0.f, a2 = 0.f, a3 = 0.f;
#pragma unroll
    for (int w = 0; w < 8; w++) {
      uint4 u = kp[w];
      uint32_t arr[4] = {u.x, u.y, u.z, u.w};
      a0 += qf[w * 8 + 0] * bf2f((unsigned short)(arr[0] & 0xffffu));
      a0 += qf[w * 8 + 1] * bf2f((unsigned short)(arr[0] >> 16));
      a1 += qf[w * 8 + 2] * bf2f((unsigned short)(arr[1] & 0xffffu));
      a1 += qf[w * 8 + 3] * bf2f((unsigned short)(arr[1] >> 16));
      a2 += qf[w * 8 + 4] * bf2f((unsigned short)(arr[2] & 0xffffu));
      a2 += qf[w * 8 + 5] * bf2f((unsigned short)(arr[2] >> 16));
      a3 += qf[w * 8 + 6] * bf2f((unsigned short)(arr[3] & 0xffffu));
      a3 += qf[w * 8 + 7] * bf2f((unsigned short)(arr[3] >> 16));
    }
    e[j] = ((a0 + a1) + (a2 + a3)) * 0.03125f;  // / sqrt(1024)
  }

  float mx = e[0];
#pragma unroll
  for (int j = 1; j < 16; j++) mx = fmaxf(mx, e[j]);
  float p[16];
  float sum = 0.f;
#pragma unroll
  for (int j = 0; j < 16; j++) { p[j] = __expf(e[j] - mx); sum += p[j]; }
  const float inv = 1.f / sum;

  float o[64];
#pragma unroll
  for (int d = 0; d < 64; d++) o[d] = 0.f;
  const unsigned short* vbase = base + 2048;
#pragma unroll
  for (int j = 0; j < 16; j++) {
    const float wgt = p[j] * inv;
    const uint4* vp = (const uint4*)(vbase + j * 64);
#pragma unroll
    for (int w = 0; w < 8; w++) {
      uint4 u = vp[w];
      uint32_t arr[4] = {u.x, u.y, u.z, u.w};
#pragma unroll
      for (int c = 0; c < 4; c++) {
        o[w * 8 + c * 2 + 0] += wgt * bf2f((unsigned short)(arr[c] & 0xffffu));
        o[w * 8 + c * 2 + 1] += wgt * bf2f((unsigned short)(arr[c] >> 16));
      }
    }
  }

  const long row = (long)b * 2048 + head * 128 + (s >> 4);
  unsigned short* op = out2 + row * 1024 + (long)(s & 15) * 64;
#pragma unroll
  for (int w = 0; w < 8; w++) {
    ushort8 r;
#pragma unroll
    for (int c = 0; c < 8; c++) r[c] = f2bf(o[w * 8 + c]);
    *(ushort8*)(op + w * 8) = r;
  }
}

extern "C" void kernel_launch(void* const* d_in, const int* in_sizes, int n_in,
                              void* d_out, int out_size, void* d_ws, size_t ws_size,
                              hipStream_t stream) {
  const float* x    = (const float*)d_in[0];  // [8,2048,1024]
  const float* Wqkv = (const float*)d_in[1];  // [3072,1024]
  const float* bqkv = (const float*)d_in[2];  // [3072]
  const float* Wo   = (const float*)d_in[3];  // [1024,1024]
  const float* bo   = (const float*)d_in[4];  // [1024]
  float* out = (float*)d_out;                 // [8,2048,1024] fp32

  char* ws = (char*)d_ws;
  unsigned short* x_bf    = (unsigned short*)(ws);              // 32 MB
  unsigned short* wqkv_bf = (unsigned short*)(ws + 33554432);   // 6 MB
  unsigned short* wo_bf   = (unsigned short*)(ws + 39845888);   // 2 MB
  unsigned short* qkv_bf  = (unsigned short*)(ws + 41943040);   // 96 MB
  unsigned short* out2_bf = (unsigned short*)(ws + 142606336);  // 32 MB

  cvt_all<<<10240, 256, 0, stream>>>(x, Wqkv, Wo, x_bf, wqkv_bf, wo_bf);

  dim3 g1(3072 / 256, 16384 / 128);
  gemm_qkv<<<g1, 256, 0, stream>>>(x_bf, wqkv_bf, bqkv, qkv_bf, 3072, 1024);

  attn_kernel<<<1024, 256, 0, stream>>>(qkv_bf, out2_bf);

  dim3 g2(1024 / 256, 16384 / 128);
  gemm_out<<<g2, 256, 0, stream>>>(out2_bf, wo_bf, bo, out, 1024, 1024);
}

// Round 4
// 340.937 us; speedup vs baseline: 1.7681x; 1.7681x over previous
//
#include <hip/hip_runtime.h>
#include <hip/hip_bf16.h>
#include <stdint.h>

// B=8, N=2048, E=1024, H=16, D=64 -> M = B*N = 16384.
// qkv row layout per token: [3][H=16][D=64] = 3072 elems

typedef __attribute__((ext_vector_type(8))) short short8;
typedef __attribute__((ext_vector_type(8))) unsigned short ushort8;
typedef __attribute__((ext_vector_type(16))) float floatx16;

__device__ __forceinline__ unsigned short f2bf(float f) {
  union { float f; uint32_t u; } x; x.f = f;
  uint32_t u = x.u;
  return (unsigned short)((u + 0x7fffu + ((u >> 16) & 1u)) >> 16);  // RNE
}
__device__ __forceinline__ float bf2f(unsigned short s) {
  union { uint32_t u; float f; } x; x.u = ((uint32_t)s) << 16; return x.f;
}
__device__ __forceinline__ void unpack8(uint4 u, float* f) {
  f[0] = bf2f((unsigned short)(u.x & 0xffffu)); f[1] = bf2f((unsigned short)(u.x >> 16));
  f[2] = bf2f((unsigned short)(u.y & 0xffffu)); f[3] = bf2f((unsigned short)(u.y >> 16));
  f[4] = bf2f((unsigned short)(u.z & 0xffffu)); f[5] = bf2f((unsigned short)(u.z >> 16));
  f[6] = bf2f((unsigned short)(u.w & 0xffffu)); f[7] = bf2f((unsigned short)(u.w >> 16));
}

// ---------------- fused fp32 -> bf16 cast ----------------
// 8-elem groups: x 2,097,152 | Wqkv 393,216 | Wo 131,072 -> 2,621,440 total
__global__ __launch_bounds__(256) void cvt_all(const float* __restrict__ x,
                                               const float* __restrict__ w1,
                                               const float* __restrict__ w2,
                                               unsigned short* __restrict__ xb,
                                               unsigned short* __restrict__ w1b,
                                               unsigned short* __restrict__ w2b) {
  int i = blockIdx.x * 256 + threadIdx.x;
  const float* src;
  unsigned short* dst;
  if (i < 2097152) {
    src = x; dst = xb;
  } else if (i < 2097152 + 393216) {
    i -= 2097152; src = w1; dst = w1b;
  } else {
    i -= 2490368; src = w2; dst = w2b;
  }
  long base = (long)i * 8;
  const float4* p = (const float4*)(src + base);
  float4 a = p[0], b = p[1];
  ushort8 r;
  r[0] = f2bf(a.x); r[1] = f2bf(a.y); r[2] = f2bf(a.z); r[3] = f2bf(a.w);
  r[4] = f2bf(b.x); r[5] = f2bf(b.y); r[6] = f2bf(b.z); r[7] = f2bf(b.w);
  *(ushort8*)(dst + base) = r;
}

// ---------------- async global->LDS, 16B per lane ----------------
__device__ __forceinline__ void gl2lds16(const void* g, void* l) {
  __builtin_amdgcn_global_load_lds(
      (const uint32_t __attribute__((address_space(1)))*)g,
      (uint32_t __attribute__((address_space(3)))*)(uint32_t)(uintptr_t)l,
      16, 0, 0);
}

// ---------------- bf16 GEMM (round-2 measured config): C = A*B^T + bias ----------------
// 128x128 tile, BK=64, 4 waves of 64x64 = 2x2 mfma_f32_32x32x16_bf16.
// XOR-swizzled LDS: chunk L = r*8 + (c ^ (r&7)).
template <bool OUT_BF16>
__device__ __forceinline__ void gemm_core(const unsigned short* __restrict__ A,
                                          const unsigned short* __restrict__ Bm,
                                          const float* __restrict__ bias,
                                          void* __restrict__ Cout, int N, int K) {
  __shared__ __align__(16) unsigned short lA[128 * 64];
  __shared__ __align__(16) unsigned short lB[128 * 64];
  const int tid = threadIdx.x;
  const int lane = tid & 63;
  const int wave = tid >> 6;
  const long row0 = (long)blockIdx.y * 128;
  const long col0 = (long)blockIdx.x * 128;
  const int wr = (wave & 1) * 64;
  const int wc = (wave >> 1) * 64;
  const int l32 = lane & 31;
  const int lhi = lane >> 5;
  const int l7 = lane & 7;

  floatx16 acc[2][2] = {};

  const int rstage = tid >> 3;
  const int cstage = (tid & 7) ^ (rstage & 7);
  const unsigned short* gA0 = A + (row0 + rstage) * (long)K + cstage * 8;
  const unsigned short* gB0 = Bm + (col0 + rstage) * (long)K + cstage * 8;
  char* ldsA0 = (char*)lA + tid * 16;
  char* ldsB0 = (char*)lB + tid * 16;
  const long rowstep = (long)32 * K;

  int aRow[2], bRow[2], sOff[4];
#pragma unroll
  for (int i = 0; i < 2; i++) aRow[i] = (wr + i * 32 + l32) * 128;
#pragma unroll
  for (int j = 0; j < 2; j++) bRow[j] = (wc + j * 32 + l32) * 128;
#pragma unroll
  for (int s = 0; s < 4; s++) sOff[s] = ((2 * s + lhi) ^ l7) * 16;

  for (int k0 = 0; k0 < K; k0 += 64) {
    __syncthreads();
#pragma unroll
    for (int p = 0; p < 4; p++) {
      gl2lds16(gA0 + p * rowstep + k0, ldsA0 + p * 4096);
      gl2lds16(gB0 + p * rowstep + k0, ldsB0 + p * 4096);
    }
    __syncthreads();

#pragma unroll
    for (int s = 0; s < 4; s++) {
      short8 a0 = *(const short8*)((char*)lA + aRow[0] + sOff[s]);
      short8 a1 = *(const short8*)((char*)lA + aRow[1] + sOff[s]);
      short8 b0 = *(const short8*)((char*)lB + bRow[0] + sOff[s]);
      short8 b1 = *(const short8*)((char*)lB + bRow[1] + sOff[s]);
      acc[0][0] = __builtin_amdgcn_mfma_f32_32x32x16_bf16(a0, b0, acc[0][0], 0, 0, 0);
      acc[0][1] = __builtin_amdgcn_mfma_f32_32x32x16_bf16(a0, b1, acc[0][1], 0, 0, 0);
      acc[1][0] = __builtin_amdgcn_mfma_f32_32x32x16_bf16(a1, b0, acc[1][0], 0, 0, 0);
      acc[1][1] = __builtin_amdgcn_mfma_f32_32x32x16_bf16(a1, b1, acc[1][1], 0, 0, 0);
    }
  }

  float bv[2];
#pragma unroll
  for (int j = 0; j < 2; j++) bv[j] = bias[col0 + wc + j * 32 + l32];

#pragma unroll
  for (int i = 0; i < 2; i++) {
#pragma unroll
    for (int j = 0; j < 2; j++) {
      const long col = col0 + wc + j * 32 + l32;
      const long rbase = row0 + wr + i * 32 + 4 * lhi;
#pragma unroll
      for (int reg = 0; reg < 16; reg++) {
        const long row = rbase + (reg & 3) + 8 * (reg >> 2);
        float v = acc[i][j][reg] + bv[j];
        if (OUT_BF16)
          ((unsigned short*)Cout)[row * N + col] = f2bf(v);
        else
          ((float*)Cout)[row * N + col] = v;
      }
    }
  }
}

__global__ __launch_bounds__(256) void gemm_qkv(const unsigned short* __restrict__ A,
                                                const unsigned short* __restrict__ Bm,
                                                const float* __restrict__ bias,
                                                unsigned short* __restrict__ Cout,
                                                int N, int K) {
  gemm_core<true>(A, Bm, bias, Cout, N, K);
}

__global__ __launch_bounds__(256) void gemm_out(const unsigned short* __restrict__ A,
                                                const unsigned short* __restrict__ Bm,
                                                const float* __restrict__ bias,
                                                float* __restrict__ Cout,
                                                int N, int K) {
  gemm_core<false>(A, Bm, bias, Cout, N, K);
}

// ---------------- per-token cross-head attention, 4 lanes per (token,head) ----------------
// Thread t: sub = t&3 owns d-range [sub*16, sub*16+16); pair = t>>2 = (token,head).
// energy[j] = sum_d Q[head][d]*K[j][d] / 32 (full dot via __shfl_xor over 4 sub-lanes);
// softmax over j (head axis); o[d] = sum_j p[j]*V[j][d].
// Raw-reshape scramble: row = b*2048 + head*128 + s/16, col = (s%16)*64 + d.
__global__ __launch_bounds__(256) void attn_kernel(const unsigned short* __restrict__ qkv,
                                                   unsigned short* __restrict__ out2) {
  const int t = blockIdx.x * 256 + threadIdx.x;
  const int sub = t & 3;
  const int pair = t >> 2;
  const int head = pair & 15;
  const int token = pair >> 4;
  const int b = token >> 11;
  const int s = token & 2047;
  const unsigned short* base = qkv + (long)token * 3072;

  // q sub-range: 16 elems
  float qf[16];
  {
    const uint4* qp = (const uint4*)(base + head * 64 + sub * 16);
    unpack8(qp[0], qf);
    unpack8(qp[1], qf + 8);
  }

  // energy (softmax prob overwrites in place)
  float e[16];
  const unsigned short* kbase = base + 1024 + sub * 16;
  for (int j = 0; j < 16; j++) {
    const uint4* kp = (const uint4*)(kbase + j * 64);
    float kf[16];
    unpack8(kp[0], kf);
    unpack8(kp[1], kf + 8);
    float a0 = 0.f, a1 = 0.f, a2 = 0.f, a3 = 0.f;
#pragma unroll
    for (int c = 0; c < 4; c++) {
      a0 += qf[c] * kf[c];
      a1 += qf[c + 4] * kf[c + 4];
      a2 += qf[c + 8] * kf[c + 8];
      a3 += qf[c + 12] * kf[c + 12];
    }
    float ej = (a0 + a1) + (a2 + a3);
    ej += __shfl_xor(ej, 1);
    ej += __shfl_xor(ej, 2);
    e[j] = ej * 0.03125f;  // / sqrt(1024)
  }

  float mx = e[0];
#pragma unroll
  for (int j = 1; j < 16; j++) mx = fmaxf(mx, e[j]);
  float sum = 0.f;
#pragma unroll
  for (int j = 0; j < 16; j++) { e[j] = __expf(e[j] - mx); sum += e[j]; }
  const float inv = 1.f / sum;

  // o = sum_j p[j] * V[j][sub-range]
  float o[16];
#pragma unroll
  for (int d = 0; d < 16; d++) o[d] = 0.f;
  const unsigned short* vbase = base + 2048 + sub * 16;
  for (int j = 0; j < 16; j++) {
    const float wgt = e[j] * inv;
    const uint4* vp = (const uint4*)(vbase + j * 64);
    float vf[16];
    unpack8(vp[0], vf);
    unpack8(vp[1], vf + 8);
#pragma unroll
    for (int d = 0; d < 16; d++) o[d] += wgt * vf[d];
  }

  const long row = (long)b * 2048 + head * 128 + (s >> 4);
  unsigned short* op = out2 + row * 1024 + (long)(s & 15) * 64 + sub * 16;
#pragma unroll
  for (int w = 0; w < 2; w++) {
    ushort8 r;
#pragma unroll
    for (int c = 0; c < 8; c++) r[c] = f2bf(o[w * 8 + c]);
    *(ushort8*)(op + w * 8) = r;
  }
}

extern "C" void kernel_launch(void* const* d_in, const int* in_sizes, int n_in,
                              void* d_out, int out_size, void* d_ws, size_t ws_size,
                              hipStream_t stream) {
  const float* x    = (const float*)d_in[0];  // [8,2048,1024]
  const float* Wqkv = (const float*)d_in[1];  // [3072,1024]
  const float* bqkv = (const float*)d_in[2];  // [3072]
  const float* Wo   = (const float*)d_in[3];  // [1024,1024]
  const float* bo   = (const float*)d_in[4];  // [1024]
  float* out = (float*)d_out;                 // [8,2048,1024] fp32

  char* ws = (char*)d_ws;
  unsigned short* x_bf    = (unsigned short*)(ws);              // 32 MB
  unsigned short* wqkv_bf = (unsigned short*)(ws + 33554432);   // 6 MB
  unsigned short* wo_bf   = (unsigned short*)(ws + 39845888);   // 2 MB
  unsigned short* qkv_bf  = (unsigned short*)(ws + 41943040);   // 96 MB
  unsigned short* out2_bf = (unsigned short*)(ws + 142606336);  // 32 MB

  cvt_all<<<10240, 256, 0, stream>>>(x, Wqkv, Wo, x_bf, wqkv_bf, wo_bf);

  dim3 g1(3072 / 128, 16384 / 128);
  gemm_qkv<<<g1, 256, 0, stream>>>(x_bf, wqkv_bf, bqkv, qkv_bf, 3072, 1024);

  // 16384 tokens * 16 heads * 4 sub-lanes = 1,048,576 threads
  attn_kernel<<<4096, 256, 0, stream>>>(qkv_bf, out2_bf);

  dim3 g2(1024 / 128, 16384 / 128);
  gemm_out<<<g2, 256, 0, stream>>>(out2_bf, wo_bf, bo, out, 1024, 1024);
}